// Round 7
// baseline (1777.833 us; speedup 1.0000x reference)
//
#include <hip/hip_runtime.h>
#include <hip/hip_bf16.h>
#include <math.h>

#define TM1 16
#define TT 17

typedef __attribute__((ext_vector_type(8))) __bf16 bf16x8;
typedef __attribute__((ext_vector_type(4))) float f32x4;

// ---------------- workspace layout (float units) ----------------
#define OFF_STATS  0          // 32
#define OFF_BSTATS 32         // 512*32 = 16384
#define OFF_SPB    16416      // 512*256 bf16 = 65536 f
#define OFF_PWB    81952      // 256*512 bf16 = 65536 f
#define OFF_WCOMB  147488     // 1536*768 bf16 = 589824 f
// ends at 737312 floats ~= 2.95 MB

// prep: pack pw -> pwb bf16; build wcomb[1536][768] = [wih(K 0..255) | whh(K 256..767)]
__global__ void prep_k(const float* __restrict__ wih, const float* __restrict__ whh,
                       const float* __restrict__ pw,
                       __hip_bfloat16* __restrict__ pwb,
                       __hip_bfloat16* __restrict__ wcomb) {
  int i = blockIdx.x * blockDim.x + threadIdx.x;
  int st = gridDim.x * blockDim.x;
  for (int j = i; j < 256 * 512; j += st) pwb[j] = __float2bfloat16(pw[j]);
  for (int j = i; j < 1536 * 768; j += st) {
    int r = j / 768, k = j % 768;
    float v = (k < 256) ? wih[r * 258 + k] : whh[r * 512 + (k - 256)];
    wcomb[j] = __float2bfloat16(v);
  }
}

// ---------------- Encoder pass A: conv + per-block channel sum/sumsq ----------------
__global__ __launch_bounds__(256) void enc_conv_stats(const float* __restrict__ x,
                                                      const float* __restrict__ cw,
                                                      float* __restrict__ bstats) {
  __shared__ float imgp[2 * 66 * 66];
  __shared__ float reds[4][16], redq[4][16];
  const int b = blockIdx.x, tid = threadIdx.x;
  const int wv = tid >> 6;
  for (int i = tid; i < 2 * 66 * 66; i += 256) imgp[i] = 0.0f;
  __syncthreads();
  const float* xb = x + b * 8192;
  for (int i = tid; i < 8192; i += 256) {
    int ci = i >> 12, rem = i & 4095, y = rem >> 6, xx = rem & 63;
    imgp[ci * 4356 + (y + 1) * 66 + (xx + 1)] = xb[i];
  }
  __syncthreads();

  for (int c4 = 0; c4 < 4; ++c4) {
    float w0[18], w1[18], w2[18], w3[18];
#pragma unroll
    for (int k = 0; k < 18; ++k) {
      w0[k] = cw[(c4 * 4 + 0) * 18 + k];
      w1[k] = cw[(c4 * 4 + 1) * 18 + k];
      w2[k] = cw[(c4 * 4 + 2) * 18 + k];
      w3[k] = cw[(c4 * 4 + 3) * 18 + k];
    }
    float s0 = 0, s1 = 0, s2 = 0, s3 = 0, q0 = 0, q1 = 0, q2 = 0, q3 = 0;
    for (int p = tid; p < 4096; p += 256) {
      int y = p >> 6, xx = p & 63;
      float v[18];
#pragma unroll
      for (int ci = 0; ci < 2; ++ci)
#pragma unroll
        for (int dy = 0; dy < 3; ++dy)
#pragma unroll
          for (int dx = 0; dx < 3; ++dx)
            v[ci * 9 + dy * 3 + dx] = imgp[ci * 4356 + (y + dy) * 66 + (xx + dx)];
      float a0 = 0, a1 = 0, a2 = 0, a3 = 0;
#pragma unroll
      for (int k = 0; k < 18; ++k) {
        a0 = fmaf(w0[k], v[k], a0);
        a1 = fmaf(w1[k], v[k], a1);
        a2 = fmaf(w2[k], v[k], a2);
        a3 = fmaf(w3[k], v[k], a3);
      }
      s0 += a0; q0 = fmaf(a0, a0, q0);
      s1 += a1; q1 = fmaf(a1, a1, q1);
      s2 += a2; q2 = fmaf(a2, a2, q2);
      s3 += a3; q3 = fmaf(a3, a3, q3);
    }
#pragma unroll
    for (int off = 32; off >= 1; off >>= 1) {
      s0 += __shfl_down(s0, off); q0 += __shfl_down(q0, off);
      s1 += __shfl_down(s1, off); q1 += __shfl_down(q1, off);
      s2 += __shfl_down(s2, off); q2 += __shfl_down(q2, off);
      s3 += __shfl_down(s3, off); q3 += __shfl_down(q3, off);
    }
    if ((tid & 63) == 0) {
      reds[wv][c4 * 4 + 0] = s0; redq[wv][c4 * 4 + 0] = q0;
      reds[wv][c4 * 4 + 1] = s1; redq[wv][c4 * 4 + 1] = q1;
      reds[wv][c4 * 4 + 2] = s2; redq[wv][c4 * 4 + 2] = q2;
      reds[wv][c4 * 4 + 3] = s3; redq[wv][c4 * 4 + 3] = q3;
    }
  }
  __syncthreads();
  if (tid < 16)
    bstats[b * 32 + tid] = reds[0][tid] + reds[1][tid] + reds[2][tid] + reds[3][tid];
  else if (tid < 32) {
    int c = tid - 16;
    bstats[b * 32 + tid] = redq[0][c] + redq[1][c] + redq[2][c] + redq[3][c];
  }
}

// reduce 512 x 32 partials -> 32 stats (deterministic, no atomics)
__global__ __launch_bounds__(256) void reduce_stats_k(const float* __restrict__ bstats,
                                                      float* __restrict__ stats) {
  __shared__ float acc[8][32];
  const int c = threadIdx.x & 31, part = threadIdx.x >> 5;
  float s = 0;
  for (int b = part; b < 512; b += 8) s += bstats[b * 32 + c];
  acc[part][c] = s;
  __syncthreads();
  if (threadIdx.x < 32) {
    float t = 0;
#pragma unroll
    for (int p = 0; p < 8; ++p) t += acc[p][threadIdx.x];
    stats[threadIdx.x] = t;
  }
}

// ---- Encoder pass B: conv + BN + relu + maxpool + avgpool + FC -> s0 ----
__global__ __launch_bounds__(256) void enc_finish(const float* __restrict__ x,
                                                  const float* __restrict__ cw,
                                                  const float* __restrict__ stats,
                                                  const float* __restrict__ gamma,
                                                  const float* __restrict__ beta,
                                                  const float* __restrict__ fcw,
                                                  const float* __restrict__ fcb,
                                                  __hip_bfloat16* __restrict__ spb,
                                                  float* __restrict__ out) {
  __shared__ float imgp[2 * 66 * 66];
  __shared__ float red[4][16];
  __shared__ float plds[16];
  const int b = blockIdx.x, tid = threadIdx.x;
  for (int i = tid; i < 2 * 66 * 66; i += 256) imgp[i] = 0.0f;
  __syncthreads();
  const float* xb = x + b * 8192;
  for (int i = tid; i < 8192; i += 256) {
    int ci = i >> 12, rem = i & 4095, y = rem >> 6, xx = rem & 63;
    imgp[ci * 4356 + (y + 1) * 66 + (xx + 1)] = xb[i];
  }
  __syncthreads();

  const float invN = 1.0f / (512.0f * 4096.0f);
  const int wv = tid >> 6;

  for (int c4 = 0; c4 < 4; ++c4) {
    float w0[18], w1[18], w2[18], w3[18];
#pragma unroll
    for (int k = 0; k < 18; ++k) {
      w0[k] = cw[(c4 * 4 + 0) * 18 + k];
      w1[k] = cw[(c4 * 4 + 1) * 18 + k];
      w2[k] = cw[(c4 * 4 + 2) * 18 + k];
      w3[k] = cw[(c4 * 4 + 3) * 18 + k];
    }
    float sc0, sc1, sc2, sc3, sh0, sh1, sh2, sh3;
    {
      int c = c4 * 4 + 0; float m = stats[c] * invN; float var = stats[16 + c] * invN - m * m;
      float isd = rsqrtf(var + 1e-5f); sc0 = gamma[c] * isd; sh0 = beta[c] - m * sc0;
      c = c4 * 4 + 1; m = stats[c] * invN; var = stats[16 + c] * invN - m * m;
      isd = rsqrtf(var + 1e-5f); sc1 = gamma[c] * isd; sh1 = beta[c] - m * sc1;
      c = c4 * 4 + 2; m = stats[c] * invN; var = stats[16 + c] * invN - m * m;
      isd = rsqrtf(var + 1e-5f); sc2 = gamma[c] * isd; sh2 = beta[c] - m * sc2;
      c = c4 * 4 + 3; m = stats[c] * invN; var = stats[16 + c] * invN - m * m;
      isd = rsqrtf(var + 1e-5f); sc3 = gamma[c] * isd; sh3 = beta[c] - m * sc3;
    }
    float p0 = 0, p1 = 0, p2 = 0, p3 = 0;
    for (int q = tid; q < 1024; q += 256) {
      int py = q >> 5, px = q & 31;
      float m0 = 0, m1 = 0, m2 = 0, m3 = 0;
#pragma unroll
      for (int sy = 0; sy < 2; ++sy)
#pragma unroll
        for (int sx = 0; sx < 2; ++sx) {
          int y = 2 * py + sy, xx = 2 * px + sx;
          float v[18];
#pragma unroll
          for (int ci = 0; ci < 2; ++ci)
#pragma unroll
            for (int dy = 0; dy < 3; ++dy)
#pragma unroll
              for (int dx = 0; dx < 3; ++dx)
                v[ci * 9 + dy * 3 + dx] = imgp[ci * 4356 + (y + dy) * 66 + (xx + dx)];
          float a0 = 0, a1 = 0, a2 = 0, a3 = 0;
#pragma unroll
          for (int k = 0; k < 18; ++k) {
            a0 = fmaf(w0[k], v[k], a0);
            a1 = fmaf(w1[k], v[k], a1);
            a2 = fmaf(w2[k], v[k], a2);
            a3 = fmaf(w3[k], v[k], a3);
          }
          m0 = fmaxf(m0, fmaxf(fmaf(a0, sc0, sh0), 0.0f));
          m1 = fmaxf(m1, fmaxf(fmaf(a1, sc1, sh1), 0.0f));
          m2 = fmaxf(m2, fmaxf(fmaf(a2, sc2, sh2), 0.0f));
          m3 = fmaxf(m3, fmaxf(fmaf(a3, sc3, sh3), 0.0f));
        }
      p0 += m0; p1 += m1; p2 += m2; p3 += m3;
    }
#pragma unroll
    for (int off = 32; off >= 1; off >>= 1) {
      p0 += __shfl_down(p0, off);
      p1 += __shfl_down(p1, off);
      p2 += __shfl_down(p2, off);
      p3 += __shfl_down(p3, off);
    }
    if ((tid & 63) == 0) {
      red[wv][c4 * 4 + 0] = p0;
      red[wv][c4 * 4 + 1] = p1;
      red[wv][c4 * 4 + 2] = p2;
      red[wv][c4 * 4 + 3] = p3;
    }
  }
  __syncthreads();
  if (tid < 16)
    plds[tid] = (red[0][tid] + red[1][tid] + red[2][tid] + red[3][tid]) * (1.0f / 1024.0f);
  __syncthreads();

  float acc = fcb[tid];
#pragma unroll
  for (int c = 0; c < 16; ++c) acc = fmaf(plds[c], fcw[tid * 16 + c], acc);
  spb[b * 256 + tid] = __float2bfloat16(acc);
  out[(b * TT + 0) * 256 + tid] = acc;
}

// ---------------- Band scan: 32 blocks x 512 thr, ZERO inter-block deps ----------------
// Block owns rows [bid*16, +16) and ALL cols; only __syncthreads() sync.
// h fp32 stays in registers (stationary); h/s bf16 in XOR-swizzled LDS
// (elem = r*W + (c ^ ((r&7)<<3)) -> uniform LDS bank groups for A-frag reads).
// Weights stream from (XCD-resident) L2 every step: 2.6 MB/step/CU, TA-bound ~4 us/step.
__global__ __launch_bounds__(512) void scan_band(
    const __hip_bfloat16* __restrict__ spb,    // 512x256
    const __hip_bfloat16* __restrict__ wcomb,  // [1536][768] packed [wih|whh]
    const __hip_bfloat16* __restrict__ pwb,    // [256][512]
    const float* __restrict__ pb,
    const float* __restrict__ actions,         // 512x16x2
    const float* __restrict__ bih, const float* __restrict__ bhh,
    const float* __restrict__ wih,             // fp32, u-tail cols 256,257
    float* __restrict__ out) {
  __shared__ __hip_bfloat16 sL[16 * 256];
  __shared__ __hip_bfloat16 hL[2][16 * 512];
  const int tid = threadIdx.x;
  const int w = tid >> 6, lane = tid & 63;
  const int l15 = lane & 15, hi = lane >> 4;
  const int row0 = blockIdx.x * 16;
  const int hc0 = w * 64;   // gates: hidden cols [hc0, hc0+64)
  const int pc0 = w * 32;   // pred: s cols [pc0, pc0+32)
  const int swl = (l15 & 7) << 3;

  // init: stage s(0) swizzled; zero hL[0]
  {
    int r = tid >> 5, c8 = (tid & 31) * 8;
    *(bf16x8*)&sL[r * 256 + (c8 ^ ((r & 7) << 3))] =
        *(const bf16x8*)(spb + (row0 + r) * 256 + c8);
    float4 z4 = {0.f, 0.f, 0.f, 0.f};
    *(float4*)&hL[0][tid * 16] = z4;
    *(float4*)&hL[0][tid * 16 + 8] = z4;
  }

  f32x4 hReg[4];
#pragma unroll
  for (int nt = 0; nt < 4; ++nt) hReg[nt] = (f32x4){0.f, 0.f, 0.f, 0.f};

  for (int t = 0; t < TM1; ++t) {
    const int cur = t & 1, nxt = cur ^ 1;

    // h A-frags (K=512) from hL[cur] — shared by pred and gates
    bf16x8 hfr[16];
#pragma unroll
    for (int kk = 0; kk < 16; ++kk)
      hfr[kk] = *(const bf16x8*)&hL[cur][l15 * 512 + ((kk * 32 + hi * 8) ^ swl)];

    if (t > 0) {
      // pred: s(t) = relu(h(t) @ P^T + pb); out slot t
      f32x4 pa0 = {0.f, 0.f, 0.f, 0.f}, pa1 = pa0;
      const __hip_bfloat16* bp = pwb + (pc0 + l15) * 512 + hi * 8;
#pragma unroll
      for (int kk = 0; kk < 16; ++kk) {
        pa0 = __builtin_amdgcn_mfma_f32_16x16x32_bf16(hfr[kk], *(const bf16x8*)(bp + kk * 32), pa0, 0, 0, 0);
        pa1 = __builtin_amdgcn_mfma_f32_16x16x32_bf16(hfr[kk], *(const bf16x8*)(bp + 16 * 512 + kk * 32), pa1, 0, 0, 0);
      }
#pragma unroll
      for (int nt2 = 0; nt2 < 2; ++nt2) {
        const int c = pc0 + nt2 * 16 + l15;
        const float bias = pb[c];
#pragma unroll
        for (int i = 0; i < 4; ++i) {
          const int r = hi * 4 + i;
          const float v = fmaxf((nt2 ? pa1[i] : pa0[i]) + bias, 0.0f);
          out[((row0 + r) * TT + t) * 256 + c] = v;
          sL[r * 256 + (c ^ ((r & 7) << 3))] = __float2bfloat16(v);
        }
      }
    }
    __syncthreads();  // sL ready (t=0: init staging covers it)

    // s A-frags (K=256)
    bf16x8 sfr[8];
#pragma unroll
    for (int kk = 0; kk < 8; ++kk)
      sfr[kk] = *(const bf16x8*)&sL[l15 * 256 + ((kk * 32 + hi * 8) ^ swl)];

    // gates: 4 hidden-col tiles x {r,z,n}; xn (s-part) and hn (h-part) split for n-gate
#pragma unroll
    for (int nt = 0; nt < 4; ++nt) {
      const int jb = hc0 + nt * 16 + l15;  // this lane's hidden col (B row)
      const __hip_bfloat16* bR = wcomb + (size_t)jb * 768 + hi * 8;
      const __hip_bfloat16* bZ = bR + 512 * 768;
      const __hip_bfloat16* bN = bZ + 512 * 768;
      f32x4 aR = {0.f, 0.f, 0.f, 0.f}, aZ = aR, aXN = aR, aHN = aR;
#pragma unroll
      for (int kk = 0; kk < 8; ++kk) {
        const bf16x8 a = sfr[kk];
        aR = __builtin_amdgcn_mfma_f32_16x16x32_bf16(a, *(const bf16x8*)(bR + kk * 32), aR, 0, 0, 0);
        aZ = __builtin_amdgcn_mfma_f32_16x16x32_bf16(a, *(const bf16x8*)(bZ + kk * 32), aZ, 0, 0, 0);
        aXN = __builtin_amdgcn_mfma_f32_16x16x32_bf16(a, *(const bf16x8*)(bN + kk * 32), aXN, 0, 0, 0);
      }
#pragma unroll
      for (int kk = 0; kk < 16; ++kk) {
        const bf16x8 a = hfr[kk];
        const int ko = 256 + kk * 32;
        aR = __builtin_amdgcn_mfma_f32_16x16x32_bf16(a, *(const bf16x8*)(bR + ko), aR, 0, 0, 0);
        aZ = __builtin_amdgcn_mfma_f32_16x16x32_bf16(a, *(const bf16x8*)(bZ + ko), aZ, 0, 0, 0);
        aHN = __builtin_amdgcn_mfma_f32_16x16x32_bf16(a, *(const bf16x8*)(bN + ko), aHN, 0, 0, 0);
      }
      // epilogue (fp32)
      const float br = bih[jb] + bhh[jb];
      const float bz = bih[512 + jb] + bhh[512 + jb];
      const float bxn = bih[1024 + jb];
      const float bhn = bhh[1024 + jb];
      const float wur = wih[jb * 258 + 256], wvr = wih[jb * 258 + 257];
      const float wuz = wih[(512 + jb) * 258 + 256], wvz = wih[(512 + jb) * 258 + 257];
      const float wun = wih[(1024 + jb) * 258 + 256], wvn = wih[(1024 + jb) * 258 + 257];
#pragma unroll
      for (int i = 0; i < 4; ++i) {
        const int r = hi * 4 + i;  // C/D: row=(lane>>4)*4+reg, col=lane&15
        const float u0 = actions[(row0 + r) * 32 + t * 2 + 0];
        const float u1 = actions[(row0 + r) * 32 + t * 2 + 1];
        const float gr = aR[i] + br + u0 * wur + u1 * wvr;
        const float gz = aZ[i] + bz + u0 * wuz + u1 * wvz;
        const float gxn = aXN[i] + bxn + u0 * wun + u1 * wvn;
        const float ghn = aHN[i] + bhn;
        const float rg = 1.0f / (1.0f + __expf(-gr));
        const float zg = 1.0f / (1.0f + __expf(-gz));
        float xn = gxn + rg * ghn;
        xn = fminf(fmaxf(xn, -15.0f), 15.0f);
        const float e = __expf(2.0f * xn);
        const float ng = (e - 1.0f) / (e + 1.0f);
        const float hnv = (1.0f - zg) * ng + zg * hReg[nt][i];
        hReg[nt][i] = hnv;
        hL[nxt][r * 512 + (jb ^ ((r & 7) << 3))] = __float2bfloat16(hnv);
      }
    }
    __syncthreads();  // hL[nxt] complete before next pred reads it
  }

  // final pred: out slot 16 from h(16) in hL[0]
  {
    bf16x8 hfr[16];
#pragma unroll
    for (int kk = 0; kk < 16; ++kk)
      hfr[kk] = *(const bf16x8*)&hL[0][l15 * 512 + ((kk * 32 + hi * 8) ^ swl)];
    f32x4 pa0 = {0.f, 0.f, 0.f, 0.f}, pa1 = pa0;
    const __hip_bfloat16* bp = pwb + (pc0 + l15) * 512 + hi * 8;
#pragma unroll
    for (int kk = 0; kk < 16; ++kk) {
      pa0 = __builtin_amdgcn_mfma_f32_16x16x32_bf16(hfr[kk], *(const bf16x8*)(bp + kk * 32), pa0, 0, 0, 0);
      pa1 = __builtin_amdgcn_mfma_f32_16x16x32_bf16(hfr[kk], *(const bf16x8*)(bp + 16 * 512 + kk * 32), pa1, 0, 0, 0);
    }
#pragma unroll
    for (int nt2 = 0; nt2 < 2; ++nt2) {
      const int c = pc0 + nt2 * 16 + l15;
      const float bias = pb[c];
#pragma unroll
      for (int i = 0; i < 4; ++i) {
        const int r = hi * 4 + i;
        out[((row0 + r) * TT + 16) * 256 + c] = fmaxf((nt2 ? pa1[i] : pa0[i]) + bias, 0.0f);
      }
    }
  }
}

extern "C" void kernel_launch(void* const* d_in, const int* in_sizes, int n_in,
                              void* d_out, int out_size, void* d_ws, size_t ws_size,
                              hipStream_t stream) {
  const float* x       = (const float*)d_in[0];
  const float* actions = (const float*)d_in[1];
  const float* cw      = (const float*)d_in[2];
  const float* gamma   = (const float*)d_in[3];
  const float* beta    = (const float*)d_in[4];
  const float* fcw     = (const float*)d_in[5];
  const float* fcb     = (const float*)d_in[6];
  const float* wih     = (const float*)d_in[7];
  const float* whh     = (const float*)d_in[8];
  const float* bih     = (const float*)d_in[9];
  const float* bhh     = (const float*)d_in[10];
  const float* pw      = (const float*)d_in[11];
  const float* pb      = (const float*)d_in[12];
  float* out = (float*)d_out;
  float* ws  = (float*)d_ws;

  float* stats  = ws + OFF_STATS;
  float* bstats = ws + OFF_BSTATS;
  __hip_bfloat16* spb   = (__hip_bfloat16*)(ws + OFF_SPB);
  __hip_bfloat16* pwb   = (__hip_bfloat16*)(ws + OFF_PWB);
  __hip_bfloat16* wcomb = (__hip_bfloat16*)(ws + OFF_WCOMB);

  prep_k<<<dim3(512), dim3(256), 0, stream>>>(wih, whh, pw, pwb, wcomb);
  enc_conv_stats<<<dim3(512), dim3(256), 0, stream>>>(x, cw, bstats);
  reduce_stats_k<<<dim3(1), dim3(256), 0, stream>>>(bstats, stats);
  enc_finish<<<dim3(512), dim3(256), 0, stream>>>(x, cw, stats, gamma, beta, fcw, fcb,
                                                  spb, out);
  scan_band<<<dim3(32), dim3(512), 0, stream>>>(spb, wcomb, pwb, pb, actions,
                                                bih, bhh, wih, out);
}

// Round 8
// 557.867 us; speedup vs baseline: 3.1868x; 3.1868x over previous
//
#include <hip/hip_runtime.h>
#include <hip/hip_bf16.h>
#include <math.h>

#define TM1 16
#define TT 17

typedef __attribute__((ext_vector_type(8))) __bf16 bf16x8;
typedef __attribute__((ext_vector_type(4))) float f32x4;

// ---------------- workspace layout (float units) ----------------
#define OFF_BSTATS 0          // 512*32 = 16384
#define OFF_SPB    16384      // 512*256 bf16 = 65536 f
#define OFF_PWB    81920      // 256*512 bf16 = 65536 f
#define OFF_WIHB   147456     // 1536*256 bf16 = 196608 f
#define OFF_WHHB   344064     // 1536*512 bf16 = 393216 f
#define OFF_HB     737280     // 2 x 512*512 bf16 = 262144 f
#define OFF_HF     999424     // 2 x 512*512 f32 = 524288 f
#define OFF_RP     1523712    // 2 x 16*8*32*256 bf16 = 1048576 f
// total 2572288 floats ~= 10.3 MB

// ---------------- Encoder pass A: conv + per-block stats; + weight bf16 prep ----------------
__global__ __launch_bounds__(256) void enc_stats_prep(
    const float* __restrict__ x, const float* __restrict__ cw,
    float* __restrict__ bstats,
    const float* __restrict__ wih, const float* __restrict__ whh,
    const float* __restrict__ pw,
    __hip_bfloat16* __restrict__ wihb, __hip_bfloat16* __restrict__ whhb,
    __hip_bfloat16* __restrict__ pwb) {
  // grid-stride weight conversion (independent of conv work)
  {
    const int n1 = 1536 * 256, n2 = 1536 * 512, n3 = 256 * 512;
    int i = blockIdx.x * 256 + threadIdx.x;
    int st = gridDim.x * 256;
    for (int j = i; j < n1 + n2 + n3; j += st) {
      if (j < n1) {
        int r = j >> 8, c = j & 255;
        wihb[j] = __float2bfloat16(wih[r * 258 + c]);
      } else if (j < n1 + n2) {
        int k = j - n1;
        whhb[k] = __float2bfloat16(whh[k]);
      } else {
        int k = j - n1 - n2;
        pwb[k] = __float2bfloat16(pw[k]);
      }
    }
  }

  __shared__ float imgp[2 * 66 * 66];
  __shared__ float reds[4][16], redq[4][16];
  const int b = blockIdx.x, tid = threadIdx.x;
  const int wv = tid >> 6;
  for (int i = tid; i < 2 * 66 * 66; i += 256) imgp[i] = 0.0f;
  __syncthreads();
  const float* xb = x + b * 8192;
  for (int i = tid; i < 8192; i += 256) {
    int ci = i >> 12, rem = i & 4095, y = rem >> 6, xx = rem & 63;
    imgp[ci * 4356 + (y + 1) * 66 + (xx + 1)] = xb[i];
  }
  __syncthreads();

  for (int c4 = 0; c4 < 4; ++c4) {
    float w0[18], w1[18], w2[18], w3[18];
#pragma unroll
    for (int k = 0; k < 18; ++k) {
      w0[k] = cw[(c4 * 4 + 0) * 18 + k];
      w1[k] = cw[(c4 * 4 + 1) * 18 + k];
      w2[k] = cw[(c4 * 4 + 2) * 18 + k];
      w3[k] = cw[(c4 * 4 + 3) * 18 + k];
    }
    float s0 = 0, s1 = 0, s2 = 0, s3 = 0, q0 = 0, q1 = 0, q2 = 0, q3 = 0;
    for (int p = tid; p < 4096; p += 256) {
      int y = p >> 6, xx = p & 63;
      float v[18];
#pragma unroll
      for (int ci = 0; ci < 2; ++ci)
#pragma unroll
        for (int dy = 0; dy < 3; ++dy)
#pragma unroll
          for (int dx = 0; dx < 3; ++dx)
            v[ci * 9 + dy * 3 + dx] = imgp[ci * 4356 + (y + dy) * 66 + (xx + dx)];
      float a0 = 0, a1 = 0, a2 = 0, a3 = 0;
#pragma unroll
      for (int k = 0; k < 18; ++k) {
        a0 = fmaf(w0[k], v[k], a0);
        a1 = fmaf(w1[k], v[k], a1);
        a2 = fmaf(w2[k], v[k], a2);
        a3 = fmaf(w3[k], v[k], a3);
      }
      s0 += a0; q0 = fmaf(a0, a0, q0);
      s1 += a1; q1 = fmaf(a1, a1, q1);
      s2 += a2; q2 = fmaf(a2, a2, q2);
      s3 += a3; q3 = fmaf(a3, a3, q3);
    }
#pragma unroll
    for (int off = 32; off >= 1; off >>= 1) {
      s0 += __shfl_down(s0, off); q0 += __shfl_down(q0, off);
      s1 += __shfl_down(s1, off); q1 += __shfl_down(q1, off);
      s2 += __shfl_down(s2, off); q2 += __shfl_down(q2, off);
      s3 += __shfl_down(s3, off); q3 += __shfl_down(q3, off);
    }
    if ((tid & 63) == 0) {
      reds[wv][c4 * 4 + 0] = s0; redq[wv][c4 * 4 + 0] = q0;
      reds[wv][c4 * 4 + 1] = s1; redq[wv][c4 * 4 + 1] = q1;
      reds[wv][c4 * 4 + 2] = s2; redq[wv][c4 * 4 + 2] = q2;
      reds[wv][c4 * 4 + 3] = s3; redq[wv][c4 * 4 + 3] = q3;
    }
  }
  __syncthreads();
  if (tid < 16)
    bstats[b * 32 + tid] = reds[0][tid] + reds[1][tid] + reds[2][tid] + reds[3][tid];
  else if (tid < 32) {
    int c = tid - 16;
    bstats[b * 32 + tid] = redq[0][c] + redq[1][c] + redq[2][c] + redq[3][c];
  }
}

// ---- Encoder pass B: in-block stats reduce + conv + BN + relu + pools + FC -> s0 ----
__global__ __launch_bounds__(256) void enc_finish(const float* __restrict__ x,
                                                  const float* __restrict__ cw,
                                                  const float* __restrict__ bstats,
                                                  const float* __restrict__ gamma,
                                                  const float* __restrict__ beta,
                                                  const float* __restrict__ fcw,
                                                  const float* __restrict__ fcb,
                                                  __hip_bfloat16* __restrict__ spb,
                                                  float* __restrict__ out) {
  __shared__ float imgp[2 * 66 * 66];
  __shared__ float red[4][16];
  __shared__ float plds[16];
  __shared__ float statsL[32];
  __shared__ float racc[8][32];
  const int b = blockIdx.x, tid = threadIdx.x;

  // reduce 512x32 partials -> 32 stats (every block, redundant but launch-free)
  {
    const int c = tid & 31, part = tid >> 5;
    float s = 0;
    for (int bb = part; bb < 512; bb += 8) s += bstats[bb * 32 + c];
    racc[part][c] = s;
  }
  for (int i = tid; i < 2 * 66 * 66; i += 256) imgp[i] = 0.0f;
  __syncthreads();
  if (tid < 32) {
    float v = 0;
#pragma unroll
    for (int p = 0; p < 8; ++p) v += racc[p][tid];
    statsL[tid] = v;
  }
  const float* xb = x + b * 8192;
  for (int i = tid; i < 8192; i += 256) {
    int ci = i >> 12, rem = i & 4095, y = rem >> 6, xx = rem & 63;
    imgp[ci * 4356 + (y + 1) * 66 + (xx + 1)] = xb[i];
  }
  __syncthreads();

  const float invN = 1.0f / (512.0f * 4096.0f);
  const int wv = tid >> 6;

  for (int c4 = 0; c4 < 4; ++c4) {
    float w0[18], w1[18], w2[18], w3[18];
#pragma unroll
    for (int k = 0; k < 18; ++k) {
      w0[k] = cw[(c4 * 4 + 0) * 18 + k];
      w1[k] = cw[(c4 * 4 + 1) * 18 + k];
      w2[k] = cw[(c4 * 4 + 2) * 18 + k];
      w3[k] = cw[(c4 * 4 + 3) * 18 + k];
    }
    float sc0, sc1, sc2, sc3, sh0, sh1, sh2, sh3;
    {
      int c = c4 * 4 + 0; float m = statsL[c] * invN; float var = statsL[16 + c] * invN - m * m;
      float isd = rsqrtf(var + 1e-5f); sc0 = gamma[c] * isd; sh0 = beta[c] - m * sc0;
      c = c4 * 4 + 1; m = statsL[c] * invN; var = statsL[16 + c] * invN - m * m;
      isd = rsqrtf(var + 1e-5f); sc1 = gamma[c] * isd; sh1 = beta[c] - m * sc1;
      c = c4 * 4 + 2; m = statsL[c] * invN; var = statsL[16 + c] * invN - m * m;
      isd = rsqrtf(var + 1e-5f); sc2 = gamma[c] * isd; sh2 = beta[c] - m * sc2;
      c = c4 * 4 + 3; m = statsL[c] * invN; var = statsL[16 + c] * invN - m * m;
      isd = rsqrtf(var + 1e-5f); sc3 = gamma[c] * isd; sh3 = beta[c] - m * sc3;
    }
    float p0 = 0, p1 = 0, p2 = 0, p3 = 0;
    for (int q = tid; q < 1024; q += 256) {
      int py = q >> 5, px = q & 31;
      float m0 = 0, m1 = 0, m2 = 0, m3 = 0;
#pragma unroll
      for (int sy = 0; sy < 2; ++sy)
#pragma unroll
        for (int sx = 0; sx < 2; ++sx) {
          int y = 2 * py + sy, xx = 2 * px + sx;
          float v[18];
#pragma unroll
          for (int ci = 0; ci < 2; ++ci)
#pragma unroll
            for (int dy = 0; dy < 3; ++dy)
#pragma unroll
              for (int dx = 0; dx < 3; ++dx)
                v[ci * 9 + dy * 3 + dx] = imgp[ci * 4356 + (y + dy) * 66 + (xx + dx)];
          float a0 = 0, a1 = 0, a2 = 0, a3 = 0;
#pragma unroll
          for (int k = 0; k < 18; ++k) {
            a0 = fmaf(w0[k], v[k], a0);
            a1 = fmaf(w1[k], v[k], a1);
            a2 = fmaf(w2[k], v[k], a2);
            a3 = fmaf(w3[k], v[k], a3);
          }
          m0 = fmaxf(m0, fmaxf(fmaf(a0, sc0, sh0), 0.0f));
          m1 = fmaxf(m1, fmaxf(fmaf(a1, sc1, sh1), 0.0f));
          m2 = fmaxf(m2, fmaxf(fmaf(a2, sc2, sh2), 0.0f));
          m3 = fmaxf(m3, fmaxf(fmaf(a3, sc3, sh3), 0.0f));
        }
      p0 += m0; p1 += m1; p2 += m2; p3 += m3;
    }
#pragma unroll
    for (int off = 32; off >= 1; off >>= 1) {
      p0 += __shfl_down(p0, off);
      p1 += __shfl_down(p1, off);
      p2 += __shfl_down(p2, off);
      p3 += __shfl_down(p3, off);
    }
    if ((tid & 63) == 0) {
      red[wv][c4 * 4 + 0] = p0;
      red[wv][c4 * 4 + 1] = p1;
      red[wv][c4 * 4 + 2] = p2;
      red[wv][c4 * 4 + 3] = p3;
    }
  }
  __syncthreads();
  if (tid < 16)
    plds[tid] = (red[0][tid] + red[1][tid] + red[2][tid] + red[3][tid]) * (1.0f / 1024.0f);
  __syncthreads();

  float acc = fcb[tid];
#pragma unroll
  for (int c = 0; c < 16; ++c) acc = fmaf(plds[c], fcw[tid * 16 + c], acc);
  spb[b * 256 + tid] = __float2bfloat16(acc);
  out[(b * TT + 0) * 256 + tid] = acc;
}

// ---------------- Fused scan step: sum-pred-partials + gates + next pred partial ----------------
// grid (8,16): by = 32-row band, bx = 64 hidden-col group. 512 threads (8 waves).
// mode 0: t==0 (s from spb, h=0, skip h-MFMAs). mode 1: normal. mode 2: final sum only.
// Split-K pred: block computes exact K=64 slice of next pred (h_new @ P^T), bf16 partial.
__global__ __launch_bounds__(512) void scan_step(
    const __hip_bfloat16* __restrict__ spb,
    const __hip_bfloat16* __restrict__ hb_in, __hip_bfloat16* __restrict__ hb_out,
    const float* __restrict__ hf_in, float* __restrict__ hf_out,
    const __hip_bfloat16* __restrict__ rp_in, __hip_bfloat16* __restrict__ rp_out,
    const __hip_bfloat16* __restrict__ wihb, const __hip_bfloat16* __restrict__ whhb,
    const __hip_bfloat16* __restrict__ pwb, const float* __restrict__ pb,
    const float* __restrict__ wih, const float* __restrict__ actions,
    const float* __restrict__ bih, const float* __restrict__ bhh,
    float* __restrict__ out, int t, int mode) {
  __shared__ __hip_bfloat16 sL[32][264];  // s(t), +8 pad -> <=2-way bank alias
  __shared__ __hip_bfloat16 hS[32][72];   // h(t+1) block tile, staged for pred-partial
  const int tid = threadIdx.x;
  const int w = tid >> 6, lane = tid & 63;
  const int l15 = lane & 15, hi = lane >> 4;
  const int bx = blockIdx.x, by = blockIdx.y;
  const int row0 = by * 32;
  const int hc0 = bx * 64;

  // ---- phase 1: materialize s(t) in LDS (and write out slot t) ----
  if (mode == 0) {
#pragma unroll
    for (int q = 0; q < 2; ++q) {
      int idx = q * 512 + tid;
      int r = idx >> 5, c8 = (idx & 31) * 8;
      *(bf16x8*)&sL[r][c8] = *(const bf16x8*)(spb + (row0 + r) * 256 + c8);
    }
  } else {
#pragma unroll
    for (int q = 0; q < 2; ++q) {
      int idx = q * 512 + tid;
      int r = idx >> 5, c8 = (idx & 31) * 8;
      float a[8];
#pragma unroll
      for (int j = 0; j < 8; ++j) a[j] = pb[c8 + j];
#pragma unroll
      for (int s = 0; s < 8; ++s) {
        bf16x8 v = *(const bf16x8*)(rp_in + (((size_t)(by * 8 + s) * 32 + r) * 256 + c8));
#pragma unroll
        for (int j = 0; j < 8; ++j) a[j] += (float)v[j];
      }
#pragma unroll
      for (int j = 0; j < 8; ++j) {
        float vv = fmaxf(a[j], 0.0f);
        if (bx == 0) out[((size_t)(row0 + r) * TT + t) * 256 + c8 + j] = vv;
        sL[r][c8 + j] = __float2bfloat16(vv);
      }
    }
  }
  __syncthreads();
  if (mode == 2) return;

  // ---- phase 2: gates. wave = (m rowhalf, cq 16-col quarter of 64) ----
  const int m = w & 1, cq = w >> 1;
  const int jb = hc0 + cq * 16 + l15;  // hidden col (B row)
  f32x4 aR = {0.f, 0.f, 0.f, 0.f}, aZ = aR, aXN = aR, aHN = aR;
  {
    const __hip_bfloat16* bR = wihb + jb * 256 + hi * 8;
    const __hip_bfloat16* bZ = wihb + (512 + jb) * 256 + hi * 8;
    const __hip_bfloat16* bN = wihb + (1024 + jb) * 256 + hi * 8;
#pragma unroll
    for (int k0 = 0; k0 < 256; k0 += 32) {
      bf16x8 a = *(const bf16x8*)&sL[m * 16 + l15][k0 + hi * 8];
      aR = __builtin_amdgcn_mfma_f32_16x16x32_bf16(a, *(const bf16x8*)(bR + k0), aR, 0, 0, 0);
      aZ = __builtin_amdgcn_mfma_f32_16x16x32_bf16(a, *(const bf16x8*)(bZ + k0), aZ, 0, 0, 0);
      aXN = __builtin_amdgcn_mfma_f32_16x16x32_bf16(a, *(const bf16x8*)(bN + k0), aXN, 0, 0, 0);
    }
  }
  if (mode != 0) {
    const __hip_bfloat16* ap = hb_in + (row0 + m * 16 + l15) * 512 + hi * 8;
    const __hip_bfloat16* bR = whhb + jb * 512 + hi * 8;
    const __hip_bfloat16* bZ = whhb + (512 + jb) * 512 + hi * 8;
    const __hip_bfloat16* bN = whhb + (1024 + jb) * 512 + hi * 8;
#pragma unroll
    for (int k0 = 0; k0 < 512; k0 += 32) {
      bf16x8 a = *(const bf16x8*)(ap + k0);
      aR = __builtin_amdgcn_mfma_f32_16x16x32_bf16(a, *(const bf16x8*)(bR + k0), aR, 0, 0, 0);
      aZ = __builtin_amdgcn_mfma_f32_16x16x32_bf16(a, *(const bf16x8*)(bZ + k0), aZ, 0, 0, 0);
      aHN = __builtin_amdgcn_mfma_f32_16x16x32_bf16(a, *(const bf16x8*)(bN + k0), aHN, 0, 0, 0);
    }
  }
  // epilogue (fp32)
  const float br = bih[jb] + bhh[jb];
  const float bz = bih[512 + jb] + bhh[512 + jb];
  const float bxn = bih[1024 + jb];
  const float bhn = bhh[1024 + jb];
  const float wur = wih[jb * 258 + 256], wvr = wih[jb * 258 + 257];
  const float wuz = wih[(512 + jb) * 258 + 256], wvz = wih[(512 + jb) * 258 + 257];
  const float wun = wih[(1024 + jb) * 258 + 256], wvn = wih[(1024 + jb) * 258 + 257];
#pragma unroll
  for (int i = 0; i < 4; ++i) {
    const int r = row0 + m * 16 + hi * 4 + i;  // C/D: row=(lane>>4)*4+reg, col=lane&15
    const float u0 = actions[r * 32 + t * 2 + 0];
    const float u1 = actions[r * 32 + t * 2 + 1];
    const float gr = aR[i] + br + u0 * wur + u1 * wvr;
    const float gz = aZ[i] + bz + u0 * wuz + u1 * wvz;
    const float gxn = aXN[i] + bxn + u0 * wun + u1 * wvn;
    const float ghn = aHN[i] + bhn;
    const float rg = 1.0f / (1.0f + __expf(-gr));
    const float zg = 1.0f / (1.0f + __expf(-gz));
    float xn = gxn + rg * ghn;
    xn = fminf(fmaxf(xn, -15.0f), 15.0f);
    const float e = __expf(2.0f * xn);
    const float ng = (e - 1.0f) / (e + 1.0f);
    const float hp = (mode == 0) ? 0.0f : hf_in[r * 512 + jb];
    const float hnv = (1.0f - zg) * ng + zg * hp;
    hf_out[r * 512 + jb] = hnv;
    hb_out[r * 512 + jb] = __float2bfloat16(hnv);
    hS[m * 16 + hi * 4 + i][cq * 16 + l15] = __float2bfloat16(hnv);
  }
  __syncthreads();

  // ---- phase 3: pred partial for step t+1: rp_out[by][bx] = hS @ P^T[:, hc0..hc0+64) ----
  // wave = (m rowhalf, cq 64-col quarter of the 256 pred cols)
  bf16x8 af0 = *(const bf16x8*)&hS[m * 16 + l15][hi * 8];
  bf16x8 af1 = *(const bf16x8*)&hS[m * 16 + l15][32 + hi * 8];
  f32x4 pa[4];
#pragma unroll
  for (int nt = 0; nt < 4; ++nt) pa[nt] = (f32x4){0.f, 0.f, 0.f, 0.f};
#pragma unroll
  for (int nt = 0; nt < 4; ++nt) {
    const int pc = cq * 64 + nt * 16 + l15;  // pred col (P row)
    const __hip_bfloat16* bp = pwb + (size_t)pc * 512 + hc0 + hi * 8;
    pa[nt] = __builtin_amdgcn_mfma_f32_16x16x32_bf16(af0, *(const bf16x8*)(bp), pa[nt], 0, 0, 0);
    pa[nt] = __builtin_amdgcn_mfma_f32_16x16x32_bf16(af1, *(const bf16x8*)(bp + 32), pa[nt], 0, 0, 0);
  }
  __hip_bfloat16* rpo = rp_out + (size_t)(by * 8 + bx) * 32 * 256;
#pragma unroll
  for (int nt = 0; nt < 4; ++nt) {
    const int pc = cq * 64 + nt * 16 + l15;
#pragma unroll
    for (int i = 0; i < 4; ++i) {
      const int r = m * 16 + hi * 4 + i;
      rpo[r * 256 + pc] = __float2bfloat16(pa[nt][i]);
    }
  }
}

extern "C" void kernel_launch(void* const* d_in, const int* in_sizes, int n_in,
                              void* d_out, int out_size, void* d_ws, size_t ws_size,
                              hipStream_t stream) {
  const float* x       = (const float*)d_in[0];
  const float* actions = (const float*)d_in[1];
  const float* cw      = (const float*)d_in[2];
  const float* gamma   = (const float*)d_in[3];
  const float* beta    = (const float*)d_in[4];
  const float* fcw     = (const float*)d_in[5];
  const float* fcb     = (const float*)d_in[6];
  const float* wih     = (const float*)d_in[7];
  const float* whh     = (const float*)d_in[8];
  const float* bih     = (const float*)d_in[9];
  const float* bhh     = (const float*)d_in[10];
  const float* pw      = (const float*)d_in[11];
  const float* pb      = (const float*)d_in[12];
  float* out = (float*)d_out;
  float* ws  = (float*)d_ws;

  float* bstats = ws + OFF_BSTATS;
  __hip_bfloat16* spb  = (__hip_bfloat16*)(ws + OFF_SPB);
  __hip_bfloat16* pwb  = (__hip_bfloat16*)(ws + OFF_PWB);
  __hip_bfloat16* wihb = (__hip_bfloat16*)(ws + OFF_WIHB);
  __hip_bfloat16* whhb = (__hip_bfloat16*)(ws + OFF_WHHB);
  __hip_bfloat16* hb0  = (__hip_bfloat16*)(ws + OFF_HB);
  __hip_bfloat16* hb1  = hb0 + 512 * 512;
  float* hf0 = ws + OFF_HF;
  float* hf1 = hf0 + 512 * 512;
  __hip_bfloat16* rp0 = (__hip_bfloat16*)(ws + OFF_RP);
  __hip_bfloat16* rp1 = rp0 + 16 * 8 * 32 * 256;

  enc_stats_prep<<<dim3(512), dim3(256), 0, stream>>>(x, cw, bstats, wih, whh, pw,
                                                      wihb, whhb, pwb);
  enc_finish<<<dim3(512), dim3(256), 0, stream>>>(x, cw, bstats, gamma, beta, fcw, fcb,
                                                  spb, out);
  for (int t = 0; t < TM1; ++t) {
    __hip_bfloat16* hbi = (t & 1) ? hb1 : hb0;
    __hip_bfloat16* hbo = (t & 1) ? hb0 : hb1;
    float* hfi = (t & 1) ? hf1 : hf0;
    float* hfo = (t & 1) ? hf0 : hf1;
    __hip_bfloat16* rpi = (t & 1) ? rp1 : rp0;
    __hip_bfloat16* rpo = (t & 1) ? rp0 : rp1;
    scan_step<<<dim3(8, 16), dim3(512), 0, stream>>>(
        spb, hbi, hbo, hfi, hfo, rpi, rpo, wihb, whhb, pwb, pb, wih, actions,
        bih, bhh, out, t, (t == 0) ? 0 : 1);
  }
  // final: sum rp (parity 16&1=0) -> s(16) -> out slot 16
  scan_step<<<dim3(1, 16), dim3(512), 0, stream>>>(
      spb, hb0, hb1, hf0, hf1, rp0, rp1, wihb, whhb, pwb, pb, wih, actions,
      bih, bhh, out, 16, 2);
}

// Round 9
// 356.057 us; speedup vs baseline: 4.9931x; 1.5668x over previous
//
#include <hip/hip_runtime.h>
#include <hip/hip_bf16.h>
#include <math.h>

#define TM1 16
#define TT 17

typedef __attribute__((ext_vector_type(8))) __bf16 bf16x8;
typedef __attribute__((ext_vector_type(4))) float f32x4;

// ---------------- workspace layout (float units) ----------------
#define OFF_BSTATS 0          // 512*32 = 16384
#define OFF_SPB    16384      // 512*256 bf16 = 65536 f
#define OFF_PWB    81920      // 256*512 bf16 = 65536 f
#define OFF_WIHB   147456     // 1536*256 bf16 = 196608 f
#define OFF_WHHB   344064     // 1536*512 bf16 = 393216 f
#define OFF_HB     737280     // 2 x 512*512 bf16 = 262144 f
// total 999424 floats ~= 4.0 MB

// ---------------- Encoder pass A: conv + per-block stats; + weight bf16 prep ----------------
__global__ __launch_bounds__(256) void enc_stats_prep(
    const float* __restrict__ x, const float* __restrict__ cw,
    float* __restrict__ bstats,
    const float* __restrict__ wih, const float* __restrict__ whh,
    const float* __restrict__ pw,
    __hip_bfloat16* __restrict__ wihb, __hip_bfloat16* __restrict__ whhb,
    __hip_bfloat16* __restrict__ pwb) {
  // grid-stride weight conversion (independent of conv work)
  {
    const int n1 = 1536 * 256, n2 = 1536 * 512, n3 = 256 * 512;
    int i = blockIdx.x * 256 + threadIdx.x;
    int st = gridDim.x * 256;
    for (int j = i; j < n1 + n2 + n3; j += st) {
      if (j < n1) {
        int r = j >> 8, c = j & 255;
        wihb[j] = __float2bfloat16(wih[r * 258 + c]);
      } else if (j < n1 + n2) {
        int k = j - n1;
        whhb[k] = __float2bfloat16(whh[k]);
      } else {
        int k = j - n1 - n2;
        pwb[k] = __float2bfloat16(pw[k]);
      }
    }
  }

  __shared__ float imgp[2 * 66 * 66];
  __shared__ float reds[4][16], redq[4][16];
  const int b = blockIdx.x, tid = threadIdx.x;
  const int wv = tid >> 6;
  for (int i = tid; i < 2 * 66 * 66; i += 256) imgp[i] = 0.0f;
  __syncthreads();
  const float* xb = x + b * 8192;
  for (int i = tid; i < 8192; i += 256) {
    int ci = i >> 12, rem = i & 4095, y = rem >> 6, xx = rem & 63;
    imgp[ci * 4356 + (y + 1) * 66 + (xx + 1)] = xb[i];
  }
  __syncthreads();

  for (int c4 = 0; c4 < 4; ++c4) {
    float w0[18], w1[18], w2[18], w3[18];
#pragma unroll
    for (int k = 0; k < 18; ++k) {
      w0[k] = cw[(c4 * 4 + 0) * 18 + k];
      w1[k] = cw[(c4 * 4 + 1) * 18 + k];
      w2[k] = cw[(c4 * 4 + 2) * 18 + k];
      w3[k] = cw[(c4 * 4 + 3) * 18 + k];
    }
    float s0 = 0, s1 = 0, s2 = 0, s3 = 0, q0 = 0, q1 = 0, q2 = 0, q3 = 0;
    for (int p = tid; p < 4096; p += 256) {
      int y = p >> 6, xx = p & 63;
      float v[18];
#pragma unroll
      for (int ci = 0; ci < 2; ++ci)
#pragma unroll
        for (int dy = 0; dy < 3; ++dy)
#pragma unroll
          for (int dx = 0; dx < 3; ++dx)
            v[ci * 9 + dy * 3 + dx] = imgp[ci * 4356 + (y + dy) * 66 + (xx + dx)];
      float a0 = 0, a1 = 0, a2 = 0, a3 = 0;
#pragma unroll
      for (int k = 0; k < 18; ++k) {
        a0 = fmaf(w0[k], v[k], a0);
        a1 = fmaf(w1[k], v[k], a1);
        a2 = fmaf(w2[k], v[k], a2);
        a3 = fmaf(w3[k], v[k], a3);
      }
      s0 += a0; q0 = fmaf(a0, a0, q0);
      s1 += a1; q1 = fmaf(a1, a1, q1);
      s2 += a2; q2 = fmaf(a2, a2, q2);
      s3 += a3; q3 = fmaf(a3, a3, q3);
    }
#pragma unroll
    for (int off = 32; off >= 1; off >>= 1) {
      s0 += __shfl_down(s0, off); q0 += __shfl_down(q0, off);
      s1 += __shfl_down(s1, off); q1 += __shfl_down(q1, off);
      s2 += __shfl_down(s2, off); q2 += __shfl_down(q2, off);
      s3 += __shfl_down(s3, off); q3 += __shfl_down(q3, off);
    }
    if ((tid & 63) == 0) {
      reds[wv][c4 * 4 + 0] = s0; redq[wv][c4 * 4 + 0] = q0;
      reds[wv][c4 * 4 + 1] = s1; redq[wv][c4 * 4 + 1] = q1;
      reds[wv][c4 * 4 + 2] = s2; redq[wv][c4 * 4 + 2] = q2;
      reds[wv][c4 * 4 + 3] = s3; redq[wv][c4 * 4 + 3] = q3;
    }
  }
  __syncthreads();
  if (tid < 16)
    bstats[b * 32 + tid] = reds[0][tid] + reds[1][tid] + reds[2][tid] + reds[3][tid];
  else if (tid < 32) {
    int c = tid - 16;
    bstats[b * 32 + tid] = redq[0][c] + redq[1][c] + redq[2][c] + redq[3][c];
  }
}

// ---- Encoder pass B: in-block stats reduce + conv + BN + relu + pools + FC -> s0 ----
__global__ __launch_bounds__(256) void enc_finish(const float* __restrict__ x,
                                                  const float* __restrict__ cw,
                                                  const float* __restrict__ bstats,
                                                  const float* __restrict__ gamma,
                                                  const float* __restrict__ beta,
                                                  const float* __restrict__ fcw,
                                                  const float* __restrict__ fcb,
                                                  __hip_bfloat16* __restrict__ spb,
                                                  float* __restrict__ out) {
  __shared__ float imgp[2 * 66 * 66];
  __shared__ float red[4][16];
  __shared__ float plds[16];
  __shared__ float statsL[32];
  __shared__ float racc[8][32];
  const int b = blockIdx.x, tid = threadIdx.x;

  {
    const int c = tid & 31, part = tid >> 5;
    float s = 0;
    for (int bb = part; bb < 512; bb += 8) s += bstats[bb * 32 + c];
    racc[part][c] = s;
  }
  for (int i = tid; i < 2 * 66 * 66; i += 256) imgp[i] = 0.0f;
  __syncthreads();
  if (tid < 32) {
    float v = 0;
#pragma unroll
    for (int p = 0; p < 8; ++p) v += racc[p][tid];
    statsL[tid] = v;
  }
  const float* xb = x + b * 8192;
  for (int i = tid; i < 8192; i += 256) {
    int ci = i >> 12, rem = i & 4095, y = rem >> 6, xx = rem & 63;
    imgp[ci * 4356 + (y + 1) * 66 + (xx + 1)] = xb[i];
  }
  __syncthreads();

  const float invN = 1.0f / (512.0f * 4096.0f);
  const int wv = tid >> 6;

  for (int c4 = 0; c4 < 4; ++c4) {
    float w0[18], w1[18], w2[18], w3[18];
#pragma unroll
    for (int k = 0; k < 18; ++k) {
      w0[k] = cw[(c4 * 4 + 0) * 18 + k];
      w1[k] = cw[(c4 * 4 + 1) * 18 + k];
      w2[k] = cw[(c4 * 4 + 2) * 18 + k];
      w3[k] = cw[(c4 * 4 + 3) * 18 + k];
    }
    float sc0, sc1, sc2, sc3, sh0, sh1, sh2, sh3;
    {
      int c = c4 * 4 + 0; float m = statsL[c] * invN; float var = statsL[16 + c] * invN - m * m;
      float isd = rsqrtf(var + 1e-5f); sc0 = gamma[c] * isd; sh0 = beta[c] - m * sc0;
      c = c4 * 4 + 1; m = statsL[c] * invN; var = statsL[16 + c] * invN - m * m;
      isd = rsqrtf(var + 1e-5f); sc1 = gamma[c] * isd; sh1 = beta[c] - m * sc1;
      c = c4 * 4 + 2; m = statsL[c] * invN; var = statsL[16 + c] * invN - m * m;
      isd = rsqrtf(var + 1e-5f); sc2 = gamma[c] * isd; sh2 = beta[c] - m * sc2;
      c = c4 * 4 + 3; m = statsL[c] * invN; var = statsL[16 + c] * invN - m * m;
      isd = rsqrtf(var + 1e-5f); sc3 = gamma[c] * isd; sh3 = beta[c] - m * sc3;
    }
    float p0 = 0, p1 = 0, p2 = 0, p3 = 0;
    for (int q = tid; q < 1024; q += 256) {
      int py = q >> 5, px = q & 31;
      float m0 = 0, m1 = 0, m2 = 0, m3 = 0;
#pragma unroll
      for (int sy = 0; sy < 2; ++sy)
#pragma unroll
        for (int sx = 0; sx < 2; ++sx) {
          int y = 2 * py + sy, xx = 2 * px + sx;
          float v[18];
#pragma unroll
          for (int ci = 0; ci < 2; ++ci)
#pragma unroll
            for (int dy = 0; dy < 3; ++dy)
#pragma unroll
              for (int dx = 0; dx < 3; ++dx)
                v[ci * 9 + dy * 3 + dx] = imgp[ci * 4356 + (y + dy) * 66 + (xx + dx)];
          float a0 = 0, a1 = 0, a2 = 0, a3 = 0;
#pragma unroll
          for (int k = 0; k < 18; ++k) {
            a0 = fmaf(w0[k], v[k], a0);
            a1 = fmaf(w1[k], v[k], a1);
            a2 = fmaf(w2[k], v[k], a2);
            a3 = fmaf(w3[k], v[k], a3);
          }
          m0 = fmaxf(m0, fmaxf(fmaf(a0, sc0, sh0), 0.0f));
          m1 = fmaxf(m1, fmaxf(fmaf(a1, sc1, sh1), 0.0f));
          m2 = fmaxf(m2, fmaxf(fmaf(a2, sc2, sh2), 0.0f));
          m3 = fmaxf(m3, fmaxf(fmaf(a3, sc3, sh3), 0.0f));
        }
      p0 += m0; p1 += m1; p2 += m2; p3 += m3;
    }
#pragma unroll
    for (int off = 32; off >= 1; off >>= 1) {
      p0 += __shfl_down(p0, off);
      p1 += __shfl_down(p1, off);
      p2 += __shfl_down(p2, off);
      p3 += __shfl_down(p3, off);
    }
    if ((tid & 63) == 0) {
      red[wv][c4 * 4 + 0] = p0;
      red[wv][c4 * 4 + 1] = p1;
      red[wv][c4 * 4 + 2] = p2;
      red[wv][c4 * 4 + 3] = p3;
    }
  }
  __syncthreads();
  if (tid < 16)
    plds[tid] = (red[0][tid] + red[1][tid] + red[2][tid] + red[3][tid]) * (1.0f / 1024.0f);
  __syncthreads();

  float acc = fcb[tid];
#pragma unroll
  for (int c = 0; c < 16; ++c) acc = fmaf(plds[c], fcw[tid * 16 + c], acc);
  spb[b * 256 + tid] = __float2bfloat16(acc);
  out[(b * TT + 0) * 256 + tid] = acc;
}

// ---------------- GRU gates, gate-per-wave: 512 blocks x 384 thr (6 waves) ----------------
// block = (cg: 32 hidden cols, band: 16 rows). wave w: (ct = w&1 col-tile-16, g = w>>2? no: g = w>>1).
// Each wave: one gate, 16x16 tile, K=768 (24 MFMAs). A-frags staged in LDS in
// fragment order (entry (kk,lane) = exactly what lane needs) -> conflict-free ds reads.
// Accs combined through LDS; waves 0,1 run the fp32 epilogue. h is bf16-only.
__global__ __launch_bounds__(384) void gru_v2(
    const __hip_bfloat16* __restrict__ spb,
    const __hip_bfloat16* __restrict__ hb_in,
    __hip_bfloat16* __restrict__ hb_out,
    const __hip_bfloat16* __restrict__ wihb,   // [1536][256]
    const __hip_bfloat16* __restrict__ whhb,   // [1536][512]
    const float* __restrict__ wih,             // fp32, u-tail cols 256,257
    const float* __restrict__ actions,         // [512][16][2]
    const float* __restrict__ bih, const float* __restrict__ bhh,
    int t) {
  __shared__ __hip_bfloat16 sF[8 * 64 * 8];    // 8KB:  s A-frags, frag-order
  __shared__ __hip_bfloat16 hF[16 * 64 * 8];   // 16KB: h A-frags, frag-order
  __shared__ float accL[4][2][256];            // 8KB:  r,z,xn,hn x coltile x elem
  const int tid = threadIdx.x;
  const int w = tid / 64, lane = tid & 63;
  const int l15 = lane & 15, hi = lane >> 4;
  const int cg = blockIdx.x, band = blockIdx.y;
  const int row0 = band * 16;
  const int ct = w & 1, g = w >> 1;

  // stage A fragments (once per block; all waves share)
  for (int i = tid; i < 512; i += 384) {
    int kk = i >> 6, ln = i & 63;
    *(bf16x8*)(sF + i * 8) =
        *(const bf16x8*)(spb + (row0 + (ln & 15)) * 256 + kk * 32 + (ln >> 4) * 8);
  }
  if (t > 0) {
    for (int i = tid; i < 1024; i += 384) {
      int kk = i >> 6, ln = i & 63;
      *(bf16x8*)(hF + i * 8) =
          *(const bf16x8*)(hb_in + (row0 + (ln & 15)) * 512 + kk * 32 + (ln >> 4) * 8);
    }
  }
  __syncthreads();

  const int cj = cg * 32 + ct * 16;
  f32x4 accS = {0.f, 0.f, 0.f, 0.f}, accH = accS;
  {
    const __hip_bfloat16* B = wihb + (g * 512 + cj + l15) * 256 + hi * 8;
#pragma unroll
    for (int kk = 0; kk < 8; ++kk) {
      bf16x8 a = *(const bf16x8*)(sF + (kk * 64 + lane) * 8);
      accS = __builtin_amdgcn_mfma_f32_16x16x32_bf16(a, *(const bf16x8*)(B + kk * 32),
                                                     accS, 0, 0, 0);
    }
  }
  if (t > 0) {
    const __hip_bfloat16* B = whhb + (g * 512 + cj + l15) * 512 + hi * 8;
#pragma unroll
    for (int kk = 0; kk < 16; ++kk) {
      bf16x8 a = *(const bf16x8*)(hF + (kk * 64 + lane) * 8);
      accH = __builtin_amdgcn_mfma_f32_16x16x32_bf16(a, *(const bf16x8*)(B + kk * 32),
                                                     accH, 0, 0, 0);
    }
  }
  // deposit accumulators (C/D: row = hi*4+i, col = l15)
  if (g < 2) {
#pragma unroll
    for (int i = 0; i < 4; ++i)
      accL[g][ct][(hi * 4 + i) * 16 + l15] = accS[i] + accH[i];
  } else {
#pragma unroll
    for (int i = 0; i < 4; ++i) {
      accL[2][ct][(hi * 4 + i) * 16 + l15] = accS[i];
      accL[3][ct][(hi * 4 + i) * 16 + l15] = accH[i];
    }
  }
  __syncthreads();

  if (w < 2) {
    f32x4 vR = *(const f32x4*)&accL[0][w][lane * 4];
    f32x4 vZ = *(const f32x4*)&accL[1][w][lane * 4];
    f32x4 vXN = *(const f32x4*)&accL[2][w][lane * 4];
    f32x4 vHN = *(const f32x4*)&accL[3][w][lane * 4];
    const int r = lane >> 2;           // e = lane*4+j -> row = lane>>2 (no carry, j<4)
    const int row = row0 + r;
    const float u0 = actions[row * 32 + t * 2 + 0];
    const float u1 = actions[row * 32 + t * 2 + 1];
#pragma unroll
    for (int j = 0; j < 4; ++j) {
      const int c = (lane & 3) * 4 + j;
      const int col = cg * 32 + w * 16 + c;
      const float br = bih[col] + bhh[col];
      const float bz = bih[512 + col] + bhh[512 + col];
      const float bxn = bih[1024 + col];
      const float bhn = bhh[1024 + col];
      const float wur = wih[col * 258 + 256], wvr = wih[col * 258 + 257];
      const float wuz = wih[(512 + col) * 258 + 256], wvz = wih[(512 + col) * 258 + 257];
      const float wun = wih[(1024 + col) * 258 + 256], wvn = wih[(1024 + col) * 258 + 257];
      const float gr = vR[j] + br + u0 * wur + u1 * wvr;
      const float gz = vZ[j] + bz + u0 * wuz + u1 * wvz;
      const float gxn = vXN[j] + bxn + u0 * wun + u1 * wvn;
      const float ghn = vHN[j] + bhn;
      const float rg = 1.0f / (1.0f + __expf(-gr));
      const float zg = 1.0f / (1.0f + __expf(-gz));
      float xn = gxn + rg * ghn;
      xn = fminf(fmaxf(xn, -15.0f), 15.0f);
      const float e = __expf(2.0f * xn);
      const float ng = (e - 1.0f) / (e + 1.0f);
      const float hp = (t > 0) ? (float)hb_in[row * 512 + col] : 0.0f;
      const float hnv = (1.0f - zg) * ng + zg * hp;
      hb_out[row * 512 + col] = __float2bfloat16(hnv);
    }
  }
}

// ---------------- pred, split-K-4: 512 blocks x 256 thr (4 waves) ----------------
// block = (pcg: 16 pred cols, band: 16 rows). wave w covers K in [w*128, w*128+128).
__global__ __launch_bounds__(256) void pred_v2(
    const __hip_bfloat16* __restrict__ hb,
    const __hip_bfloat16* __restrict__ pwb,    // [256][512]
    const float* __restrict__ pb,
    float* __restrict__ out,
    __hip_bfloat16* __restrict__ spb,
    int slot) {
  __shared__ float accL[4][256];
  const int tid = threadIdx.x;
  const int w = tid >> 6, lane = tid & 63;
  const int l15 = lane & 15, hi = lane >> 4;
  const int pcg = blockIdx.x, band = blockIdx.y;
  const int row0 = band * 16, pc0 = pcg * 16;
  f32x4 acc = {0.f, 0.f, 0.f, 0.f};
  const __hip_bfloat16* A = hb + (row0 + l15) * 512 + w * 128 + hi * 8;
  const __hip_bfloat16* B = pwb + (pc0 + l15) * 512 + w * 128 + hi * 8;
#pragma unroll
  for (int kk = 0; kk < 4; ++kk)
    acc = __builtin_amdgcn_mfma_f32_16x16x32_bf16(*(const bf16x8*)(A + kk * 32),
                                                  *(const bf16x8*)(B + kk * 32),
                                                  acc, 0, 0, 0);
#pragma unroll
  for (int i = 0; i < 4; ++i) accL[w][(hi * 4 + i) * 16 + l15] = acc[i];
  __syncthreads();
  if (w == 0) {
    f32x4 p0 = *(const f32x4*)&accL[0][lane * 4];
    f32x4 p1 = *(const f32x4*)&accL[1][lane * 4];
    f32x4 p2 = *(const f32x4*)&accL[2][lane * 4];
    f32x4 p3 = *(const f32x4*)&accL[3][lane * 4];
    const int r = lane >> 2;
    const int row = row0 + r;
    float4 ov;
    float* po = &ov.x;
#pragma unroll
    for (int j = 0; j < 4; ++j) {
      const int c = (lane & 3) * 4 + j;
      const int col = pc0 + c;
      float v = p0[j] + p1[j] + p2[j] + p3[j] + pb[col];
      v = fmaxf(v, 0.0f);
      po[j] = v;
      spb[row * 256 + col] = __float2bfloat16(v);
    }
    *(float4*)(out + ((size_t)row * TT + slot) * 256 + pc0 + (lane & 3) * 4) = ov;
  }
}

extern "C" void kernel_launch(void* const* d_in, const int* in_sizes, int n_in,
                              void* d_out, int out_size, void* d_ws, size_t ws_size,
                              hipStream_t stream) {
  const float* x       = (const float*)d_in[0];
  const float* actions = (const float*)d_in[1];
  const float* cw      = (const float*)d_in[2];
  const float* gamma   = (const float*)d_in[3];
  const float* beta    = (const float*)d_in[4];
  const float* fcw     = (const float*)d_in[5];
  const float* fcb     = (const float*)d_in[6];
  const float* wih     = (const float*)d_in[7];
  const float* whh     = (const float*)d_in[8];
  const float* bih     = (const float*)d_in[9];
  const float* bhh     = (const float*)d_in[10];
  const float* pw      = (const float*)d_in[11];
  const float* pb      = (const float*)d_in[12];
  float* out = (float*)d_out;
  float* ws  = (float*)d_ws;

  float* bstats = ws + OFF_BSTATS;
  __hip_bfloat16* spb  = (__hip_bfloat16*)(ws + OFF_SPB);
  __hip_bfloat16* pwb  = (__hip_bfloat16*)(ws + OFF_PWB);
  __hip_bfloat16* wihb = (__hip_bfloat16*)(ws + OFF_WIHB);
  __hip_bfloat16* whhb = (__hip_bfloat16*)(ws + OFF_WHHB);
  __hip_bfloat16* hb0  = (__hip_bfloat16*)(ws + OFF_HB);
  __hip_bfloat16* hb1  = hb0 + 512 * 512;

  enc_stats_prep<<<dim3(512), dim3(256), 0, stream>>>(x, cw, bstats, wih, whh, pw,
                                                      wihb, whhb, pwb);
  enc_finish<<<dim3(512), dim3(256), 0, stream>>>(x, cw, bstats, gamma, beta, fcw, fcb,
                                                  spb, out);
  for (int t = 0; t < TM1; ++t) {
    __hip_bfloat16* hbi = (t & 1) ? hb1 : hb0;
    __hip_bfloat16* hbo = (t & 1) ? hb0 : hb1;
    gru_v2<<<dim3(16, 32), dim3(384), 0, stream>>>(spb, hbi, hbo, wihb, whhb,
                                                   wih, actions, bih, bhh, t);
    pred_v2<<<dim3(16, 32), dim3(256), 0, stream>>>(hbo, pwb, pb, out, spb, t + 1);
  }
}